// Round 2
// baseline (275.233 us; speedup 1.0000x reference)
//
#include <hip/hip_runtime.h>

// Problem constants (fixed by setup_inputs)
#define DIM 512
#define NQ 64
#define BATCH 2048

typedef __bf16  bf16x8  __attribute__((ext_vector_type(8)));
typedef float   floatx4 __attribute__((ext_vector_type(4)));

static __device__ inline unsigned short f2bf(float f) {
    unsigned int u = __float_as_uint(f);
    return (unsigned short)((u + 0x7fffu + ((u >> 16) & 1u)) >> 16);  // RNE
}
static __device__ inline float bf2f(unsigned short h) {
    return __uint_as_float((unsigned int)h << 16);
}
static __device__ inline unsigned int pack2(float a, float b) {
    return (unsigned)f2bf(a) | ((unsigned)f2bf(b) << 16);
}

// Pack points fp32 (2048,512) -> bf16 Pb (2 MB, L2-resident for the GEMM)
__global__ void hsq_pack_kernel(const float* __restrict__ pts,
                                unsigned short* __restrict__ Pb) {
    const int i8 = blockIdx.x * 256 + threadIdx.x;
    const float4 v1 = *(const float4*)(pts + (size_t)i8 * 8);
    const float4 v2 = *(const float4*)(pts + (size_t)i8 * 8 + 4);
    uint4 wv;
    wv.x = pack2(v1.x, v1.y); wv.y = pack2(v1.z, v1.w);
    wv.z = pack2(v2.x, v2.y); wv.w = pack2(v2.z, v2.w);
    *(uint4*)(Pb + (size_t)i8 * 8) = wv;
}

// Expand q_coefs (n_mono,64) -> W[k][e][d] (bf16, d contiguous). norm2 partials
// as plain per-block stores (atomics were ~110 us in earlier rounds).
__global__ __launch_bounds__(256, 4)
void hsq_expand_kernel(const float* __restrict__ qc,
                       unsigned short* __restrict__ W,
                       float* __restrict__ npart) {
    const int e    = blockIdx.x;          // 0..511
    const int dblk = blockIdx.y;          // 0..3
    const int pb   = blockIdx.y * 512 + blockIdx.x;   // 0..2047
    const int wid  = threadIdx.x >> 6;
    const int k    = threadIdx.x & 63;    // lane = quadric index
    const int d0   = dblk * 128 + wid * 32;

    __shared__ unsigned short tv[64 * 136];
    __shared__ float part[4][64];

    float v[32];
#pragma unroll
    for (int s = 0; s < 32; ++s) {
        const int d = d0 + s;
        const int i = d < e ? d : e;
        const int j = d < e ? e : d;
        const int idx = i * DIM - ((i * (i - 1)) >> 1) + (j - i);
        v[s] = qc[(size_t)idx * NQ + k];
    }

    float nacc = 0.0f;
#pragma unroll
    for (int s = 0; s < 32; ++s)
        if (d0 + s >= e) nacc += v[s] * v[s];

#pragma unroll
    for (int t = 0; t < 4; ++t) {
        float sc[8];
#pragma unroll
        for (int q = 0; q < 8; ++q) {
            const int d = d0 + t * 8 + q;
            sc[q] = v[t * 8 + q] * ((d == e) ? 2.0f : 1.41421356237309515f);
        }
        uint4 w;
        w.x = pack2(sc[0], sc[1]); w.y = pack2(sc[2], sc[3]);
        w.z = pack2(sc[4], sc[5]); w.w = pack2(sc[6], sc[7]);
        *(uint4*)&tv[k * 136 + wid * 32 + t * 8] = w;
    }
    part[wid][k] = nacc;
    __syncthreads();

#pragma unroll
    for (int r = 0; r < 4; ++r) {
        const int kk = r * 16 + (threadIdx.x >> 4);
        const int u  = threadIdx.x & 15;
        const uint4 w = *(const uint4*)&tv[kk * 136 + u * 8];
        *(uint4*)(W + ((size_t)(kk * DIM + e)) * DIM + dblk * 128 + u * 8) = w;
    }
    if (threadIdx.x < 64) {
        npart[(size_t)k * 2048 + pb] =
            part[0][k] + part[1][k] + part[2][k] + part[3][k];
    }
}

// ---------------------------------------------------------------------------
// 256x256 8-phase GEMM, ONE ROUND: 256 blocks (1/CU), each block processes 4
// quadrics (k = kgrp*4+kq) back-to-back through ONE continuous pipeline.
// Global K-tile index g = 0..31; A source cycles cols (g&7)*64 (re-staged per
// k), B source steps W slab (g>>3). Per-k epilogue runs inside the pipeline
// with a DEDICATED red region (no __syncthreads -> no vmcnt(0) drain; the
// next k's B prefetch rides across it). 136 KiB dynamic LDS:
//   stages: A(buf,h) @ buf*32768 + h*8192 ; B(buf,h) @ buf*32768+16384+h*8192
//   red:    floats @ element 65536 (8 KB)
// Stage schedule per it (compute g0=2it from buf0 @p0-3, g1=2it+1 buf1 @p4-7):
//   p0: buf1.A0<-g1   p1: buf1.A1<-g1
//   p2: buf0.B0<-g2   p3: buf0.B1<-g2 ; vmcnt(4)   (it==15: vmcnt(0))
//   p4: buf0.A0<-g2   p5: buf0.A1<-g2
//   p6: buf1.B0<-g3   p7: buf1.B1<-g3 ; vmcnt(4)
// vmcnt(4) leaves exactly the 2 newest half-tiles in flight. Epilogue loads/
// stores are OLDER than the next it's stages and vmcnt retires in order, so
// the count stays conservative-correct across epilogues.
// LDS swizzle (both sides, involution): colbyte ^= (row&7)<<4 within a
// [128][64]bf16 half; global_load_lds dest stays linear, source pre-swizzled.
// ---------------------------------------------------------------------------
__global__ __launch_bounds__(512, 2)
void hsq_gemm_kernel(const unsigned short* __restrict__ Pb,
                     const unsigned short* __restrict__ W,
                     const float* __restrict__ l_coefs,
                     float2* __restrict__ part) {
    extern __shared__ unsigned short smem[];

    // bijective XCD swizzle (256 % 8 == 0): 32 consecutive wg per XCD
    const int bid  = blockIdx.x;
    const int wg   = (bid & 7) * 32 + (bid >> 3);
    const int kgrp = wg >> 4;             // 0..15 (4 quadrics each)
    const int et   = (wg >> 3) & 1;       // e-tile of 256
    const int mt   = wg & 7;              // batch tile of 256
    const int m0   = mt * 256;

    const int tid  = threadIdx.x;
    const int lane = tid & 63;
    const int w    = tid >> 6;            // 0..7
    const int wm   = w >> 2;              // 0..1
    const int wn   = w & 3;               // 0..3
    const int c    = lane & 15;
    const int quad = lane >> 4;

    // staging source (linear LDS dest; source carries the swizzle)
    const int scolb = ((tid & 7) * 16) ^ (((tid >> 3) & 7) << 4);   // bytes
    const unsigned short* pAs = Pb + (size_t)(m0 + (tid >> 3)) * DIM + (scolb >> 1);
    const unsigned short* pBs = W + (size_t)(kgrp * 4) * DIM * DIM
                                  + (size_t)(et * 256 + (tid >> 3)) * DIM + (scolb >> 1);
#define PA(g) (pAs + (size_t)((g) & 7) * 64)
#define PB(g) (pBs + (size_t)((g) >> 3) * (DIM * DIM) + (size_t)((g) & 7) * 64)

    // frag read offsets (elements); row&7 == c&7 for every frag row
    const int xorv  = (c & 7) << 4;                              // bytes
    const int koff0 = ((0 * 64 + quad * 16) ^ xorv) >> 1;
    const int koff1 = ((1 * 64 + quad * 16) ^ xorv) >> 1;
    const int awoff = wm * 8192 + c * 64;
    const int bwoff = (wn >> 1) * 8192 + (wn & 1) * 4096 + c * 64;

    float* red = (float*)&smem[65536];    // dedicated 8 KB, beyond stage area

#define STAGE_HALF(LDSELEM, GSRC) do {                                         \
    _Pragma("unroll")                                                          \
    for (int cc_ = 0; cc_ < 2; ++cc_) {                                        \
        __builtin_amdgcn_global_load_lds(                                      \
            (const __attribute__((address_space(1))) unsigned int*)            \
                ((GSRC) + (size_t)(cc_ * 64) * DIM),                           \
            (__attribute__((address_space(3))) unsigned int*)                  \
                (smem + (LDSELEM) + cc_ * 4096 + tid * 8),                     \
            16, 0, 0);                                                         \
    }                                                                          \
} while (0)

#define LOADB(BBASE) do {                                                      \
    _Pragma("unroll")                                                          \
    for (int ni_ = 0; ni_ < 4; ++ni_) {                                        \
        bfr[ni_][0] = *(const bf16x8*)(smem + (BBASE) + bwoff + ni_ * 1024 + koff0); \
        bfr[ni_][1] = *(const bf16x8*)(smem + (BBASE) + bwoff + ni_ * 1024 + koff1); \
    }                                                                          \
} while (0)

#define PHASE(ABASE, MI0, PRE_B, STAGE_AND_WAIT) do {                          \
    bf16x8 a00 = *(const bf16x8*)(smem + (ABASE) + awoff + (MI0) * 1024 + koff0);     \
    bf16x8 a01 = *(const bf16x8*)(smem + (ABASE) + awoff + (MI0) * 1024 + koff1);     \
    bf16x8 a10 = *(const bf16x8*)(smem + (ABASE) + awoff + ((MI0) + 1) * 1024 + koff0); \
    bf16x8 a11 = *(const bf16x8*)(smem + (ABASE) + awoff + ((MI0) + 1) * 1024 + koff1); \
    PRE_B;                                                                     \
    STAGE_AND_WAIT;                                                            \
    asm volatile("" ::: "memory");                                             \
    __builtin_amdgcn_s_barrier();                                              \
    asm volatile("" ::: "memory");                                             \
    __builtin_amdgcn_s_setprio(1);                                             \
    _Pragma("unroll")                                                          \
    for (int ni_ = 0; ni_ < 4; ++ni_) {                                        \
        acc[(MI0)][ni_]     = __builtin_amdgcn_mfma_f32_16x16x32_bf16(a00, bfr[ni_][0], acc[(MI0)][ni_], 0, 0, 0);     \
        acc[(MI0)][ni_]     = __builtin_amdgcn_mfma_f32_16x16x32_bf16(a01, bfr[ni_][1], acc[(MI0)][ni_], 0, 0, 0);     \
        acc[(MI0) + 1][ni_] = __builtin_amdgcn_mfma_f32_16x16x32_bf16(a10, bfr[ni_][0], acc[(MI0) + 1][ni_], 0, 0, 0); \
        acc[(MI0) + 1][ni_] = __builtin_amdgcn_mfma_f32_16x16x32_bf16(a11, bfr[ni_][1], acc[(MI0) + 1][ni_], 0, 0, 0); \
    }                                                                          \
    __builtin_amdgcn_s_setprio(0);                                             \
    asm volatile("" ::: "memory");                                             \
    __builtin_amdgcn_s_barrier();                                              \
    asm volatile("" ::: "memory");                                             \
} while (0)

    floatx4 acc[8][4];
#pragma unroll
    for (int mi = 0; mi < 8; ++mi)
#pragma unroll
        for (int ni = 0; ni < 4; ++ni)
            acc[mi][ni] = (floatx4){0.f, 0.f, 0.f, 0.f};

    bf16x8 bfr[4][2];

    const unsigned short* Pe = Pb + (size_t)(m0 + wm * 128) * DIM + et * 256 + wn * 64 + c;

    // prologue: buf0 full (g=0) + buf1.B (g=1); wait buf0, leave buf1.B riding
    STAGE_HALF(0,             PA(0));
    STAGE_HALF(8192,          PA(0) + 128 * DIM);
    STAGE_HALF(16384,         PB(0));
    STAGE_HALF(16384 + 8192,  PB(0) + 128 * DIM);
    STAGE_HALF(49152,         PB(1));
    STAGE_HALF(49152 + 8192,  PB(1) + 128 * DIM);
    asm volatile("s_waitcnt vmcnt(4)" ::: "memory");
    __builtin_amdgcn_s_barrier();
    asm volatile("" ::: "memory");

#pragma unroll 1
    for (int it = 0; it < 16; ++it) {
        const int g1 = 2 * it + 1, g2 = 2 * it + 2, g3 = 2 * it + 3;

        // ---- K-tile 2*it from buf0 ----
        PHASE(0, 0, LOADB(16384), { STAGE_HALF(32768, PA(g1)); });
        PHASE(0, 2, ((void)0),    { STAGE_HALF(32768 + 8192, PA(g1) + 128 * DIM); });
        PHASE(0, 4, ((void)0),    { if (it < 15) STAGE_HALF(16384, PB(g2)); });
        PHASE(0, 6, ((void)0), {
            if (it < 15) {
                STAGE_HALF(16384 + 8192, PB(g2) + 128 * DIM);
                asm volatile("s_waitcnt vmcnt(4)" ::: "memory");
            } else {
                asm volatile("s_waitcnt vmcnt(0)" ::: "memory");
            }
        });
        // ---- K-tile 2*it+1 from buf1 ----
        PHASE(32768, 0, LOADB(49152), { if (it < 15) STAGE_HALF(0, PA(g2)); });
        PHASE(32768, 2, ((void)0),    { if (it < 15) STAGE_HALF(8192, PA(g2) + 128 * DIM); });
        PHASE(32768, 4, ((void)0),    { if (it < 15) STAGE_HALF(49152, PB(g3)); });
        PHASE(32768, 6, ((void)0), {
            if (it < 15) {
                STAGE_HALF(49152 + 8192, PB(g3) + 128 * DIM);
                asm volatile("s_waitcnt vmcnt(4)" ::: "memory");
            }
        });

        // ---- per-quadric epilogue every 8 K-tiles (kq = it>>2) ----
        if ((it & 3) == 3) {
            const int kk = kgrp * 4 + (it >> 2);
            float lcv[4];
#pragma unroll
            for (int ni = 0; ni < 4; ++ni)
                lcv[ni] = l_coefs[(et * 256 + wn * 64 + ni * 16 + c) * NQ + kk];

#pragma unroll
            for (int mi = 0; mi < 8; ++mi)
#pragma unroll
                for (int r = 0; r < 4; ++r) {
                    const unsigned short* Prow =
                        Pe + (size_t)(mi * 16 + quad * 4 + r) * DIM;
                    float pv = 0.f, pg = 0.f;
#pragma unroll
                    for (int ni = 0; ni < 4; ++ni) {
                        const float g = acc[mi][ni][r];
                        const float l = lcv[ni];
                        pv += bf2f(Prow[ni * 16]) * (0.5f * g + l);
                        const float gq = g + l;
                        pg += gq * gq;
                    }
#pragma unroll
                    for (int off = 1; off < 16; off <<= 1) {
                        pv += __shfl_xor(pv, off);
                        pg += __shfl_xor(pg, off);
                    }
                    if (c == 0) {
                        const int row16 = mi * 16 + quad * 4 + r;
                        red[(w * 128 + row16) * 2 + 0] = pv;
                        red[(w * 128 + row16) * 2 + 1] = pg;
                    }
                }
            // raw barrier (NOT __syncthreads): keep staged prefetch in flight
            asm volatile("s_waitcnt lgkmcnt(0)" ::: "memory");
            __builtin_amdgcn_s_barrier();
            asm volatile("" ::: "memory");

            if (tid < 256) {
                const int row16 = tid & 127;
                const int wmf   = tid >> 7;
                float pv = 0.f, pg = 0.f;
#pragma unroll
                for (int wnf = 0; wnf < 4; ++wnf) {
                    const int wi = wmf * 4 + wnf;
                    pv += red[(wi * 128 + row16) * 2 + 0];
                    pg += red[(wi * 128 + row16) * 2 + 1];
                }
                part[((size_t)(et * NQ + kk)) * BATCH + m0 + wmf * 128 + row16] =
                    make_float2(pv, pg);
            }
            // reset accumulators for the next quadric
#pragma unroll
            for (int mi = 0; mi < 8; ++mi)
#pragma unroll
                for (int ni = 0; ni < 4; ++ni)
                    acc[mi][ni] = (floatx4){0.f, 0.f, 0.f, 0.f};
            // no trailing barrier needed: the next it's phase barriers (64 of
            // them) separate these red reads from the next epilogue's writes.
        }
    }
#undef PHASE
#undef LOADB
#undef STAGE_HALF
#undef PA
#undef PB
}

// Final: block per k. Reduces npart[k][*] -> norm2 in-block, then combines the
// 2 e-range partials into scores (coalesced reads).
__global__ void hsq_final_kernel(const float2* __restrict__ part,
                                 const float* __restrict__ npart,
                                 const float* __restrict__ free_coefs,
                                 float* __restrict__ out) {
    const int k = blockIdx.x;
    const int t = threadIdx.x;
    __shared__ float ws[4];

    const float4* src = (const float4*)(npart + (size_t)k * 2048);
    const float4 a = src[t * 2], b = src[t * 2 + 1];
    float s = a.x + a.y + a.z + a.w + b.x + b.y + b.z + b.w;
#pragma unroll
    for (int off = 1; off < 64; off <<= 1) s += __shfl_xor(s, off);
    if ((t & 63) == 0) ws[t >> 6] = s;
    __syncthreads();
    const float nrm = sqrtf(ws[0] + ws[1] + ws[2] + ws[3]);
    const float fc  = free_coefs[k];

#pragma unroll
    for (int i = 0; i < 8; ++i) {
        const int bidx = i * 256 + t;
        float pv = 0.f, pg = 0.f;
#pragma unroll
        for (int eb = 0; eb < 2; ++eb) {
            const float2 p = part[((size_t)(eb * NQ + k)) * BATCH + bidx];
            pv += p.x; pg += p.y;
        }
        const float vals = fabsf(pv + fc);
        out[(size_t)bidx * NQ + k] = (sqrtf(0.25f * pg + vals * nrm) - 0.5f * sqrtf(pg)) / nrm;
    }
}

extern "C" void kernel_launch(void* const* d_in, const int* in_sizes, int n_in,
                              void* d_out, int out_size, void* d_ws, size_t ws_size,
                              hipStream_t stream) {
    const float* points     = (const float*)d_in[0];  // (2048, 512)
    const float* q_coefs    = (const float*)d_in[1];  // (131328, 64)
    const float* l_coefs    = (const float*)d_in[2];  // (512, 64)
    const float* free_coefs = (const float*)d_in[3];  // (1, 64)
    float* out = (float*)d_out;                       // (2048, 64)

    char* ws = (char*)d_ws;
    unsigned short* W  = (unsigned short*)ws;                              // 32 MiB
    unsigned short* Pb = (unsigned short*)(ws + 33554432);                 // 2 MiB
    float2*         part  = (float2*)(ws + 35651584);                      // 2 MiB
    float*          npart = (float*)(ws + 37748736);                       // 512 KiB

    // 136 KiB dynamic LDS needs the opt-in (one-time; not a stream op, safe
    // under graph capture).
    static bool attr_done = false;
    if (!attr_done) {
        (void)hipFuncSetAttribute((const void*)hsq_gemm_kernel,
                                  hipFuncAttributeMaxDynamicSharedMemorySize,
                                  139264);
        attr_done = true;
    }

    hsq_pack_kernel<<<dim3(BATCH * DIM / 8 / 256), 256, 0, stream>>>(points, Pb);
    hsq_expand_kernel<<<dim3(DIM, 4), 256, 0, stream>>>(q_coefs, W, npart);
    hsq_gemm_kernel<<<dim3(256), dim3(512), 139264, stream>>>(Pb, W, l_coefs, part);
    hsq_final_kernel<<<dim3(NQ), 256, 0, stream>>>(part, npart, free_coefs, out);
}

// Round 3
// 191.645 us; speedup vs baseline: 1.4362x; 1.4362x over previous
//
#include <hip/hip_runtime.h>

// Problem constants (fixed by setup_inputs)
#define DIM 512
#define NQ 64
#define BATCH 2048

typedef __bf16  bf16x8  __attribute__((ext_vector_type(8)));
typedef float   floatx4 __attribute__((ext_vector_type(4)));

static __device__ inline unsigned short f2bf(float f) {
    unsigned int u = __float_as_uint(f);
    return (unsigned short)((u + 0x7fffu + ((u >> 16) & 1u)) >> 16);  // RNE
}
static __device__ inline float bf2f(unsigned short h) {
    return __uint_as_float((unsigned int)h << 16);
}
static __device__ inline unsigned int pack2(float a, float b) {
    return (unsigned)f2bf(a) | ((unsigned)f2bf(b) << 16);
}

// Fused pack+expand. Grid (512, 5):
//   y = 0..3 : expand q_coefs (n_mono,64) -> W[k][e][d] (bf16, d contiguous)
//              for e = blockIdx.x, d-range = y*128..y*128+127; npart partials.
//   y = 4    : pack points fp32 -> bf16 Pb (the old hsq_pack_kernel's work,
//              strip e*2048..e*2048+2047 elements).
// 512 threads (8 waves), 16 elems/thread: ~half the VGPR of the old 256-thr
// version -> __launch_bounds__(512,3) = 24 waves/CU (was 16) for the
// latency-bound scattered qc gather.
__global__ __launch_bounds__(512, 3)
void hsq_expand_kernel(const float* __restrict__ qc,
                       const float* __restrict__ pts,
                       unsigned short* __restrict__ W,
                       unsigned short* __restrict__ Pb,
                       float* __restrict__ npart) {
    const int e = blockIdx.x;             // 0..511

    if (blockIdx.y == 4) {
        // pack strip: 512 float4-groups per block, 262144 total = 2048*512/4
        const int i4 = e * 512 + threadIdx.x;
        const float4 v = *(const float4*)(pts + (size_t)i4 * 4);
        uint2 wv;
        wv.x = pack2(v.x, v.y); wv.y = pack2(v.z, v.w);
        *(uint2*)(Pb + (size_t)i4 * 4) = wv;
        return;
    }

    const int dblk = blockIdx.y;          // 0..3
    const int pb   = dblk * 512 + e;      // 0..2047
    const int wid  = threadIdx.x >> 6;    // 0..7
    const int k    = threadIdx.x & 63;    // lane = quadric index
    const int d0   = dblk * 128 + wid * 16;

    __shared__ unsigned short tv[64 * 136];
    __shared__ float part[8][64];

    float v[16];
#pragma unroll
    for (int s = 0; s < 16; ++s) {
        const int d = d0 + s;
        const int i = d < e ? d : e;
        const int j = d < e ? e : d;
        const int idx = i * DIM - ((i * (i - 1)) >> 1) + (j - i);
        v[s] = qc[(size_t)idx * NQ + k];
    }

    float nacc = 0.0f;
#pragma unroll
    for (int s = 0; s < 16; ++s)
        if (d0 + s >= e) nacc += v[s] * v[s];

#pragma unroll
    for (int t = 0; t < 2; ++t) {
        float sc[8];
#pragma unroll
        for (int q = 0; q < 8; ++q) {
            const int d = d0 + t * 8 + q;
            sc[q] = v[t * 8 + q] * ((d == e) ? 2.0f : 1.41421356237309515f);
        }
        uint4 w;
        w.x = pack2(sc[0], sc[1]); w.y = pack2(sc[2], sc[3]);
        w.z = pack2(sc[4], sc[5]); w.w = pack2(sc[6], sc[7]);
        *(uint4*)&tv[k * 136 + wid * 16 + t * 8] = w;
    }
    part[wid][k] = nacc;
    __syncthreads();

#pragma unroll
    for (int r = 0; r < 2; ++r) {
        const int kk = r * 32 + (threadIdx.x >> 4);
        const int u  = threadIdx.x & 15;
        const uint4 w = *(const uint4*)&tv[kk * 136 + u * 8];
        *(uint4*)(W + ((size_t)(kk * DIM + e)) * DIM + dblk * 128 + u * 8) = w;
    }
    if (threadIdx.x < 64) {
        npart[(size_t)k * 2048 + pb] =
            part[0][k] + part[1][k] + part[2][k] + part[3][k] +
            part[4][k] + part[5][k] + part[6][k] + part[7][k];
    }
}

// ---------------------------------------------------------------------------
// 256x256 8-phase GEMM (round-1 version, measured 105.5 us / MfmaUtil 26.7 /
// FETCH 25 MB): T1 xcd-swizzle + T2 lds-swizzle + T3/T4 counted vmcnt + T5
// setprio. 512 threads = 8 waves (2M x 4N), BK=64, K=512 -> 8 K-tiles, 2 per
// iteration, 4 iterations, ONE k per block (round-2 lesson: multi-k per block
// breaks L2 slab sharing via inter-block drift -> 4x HBM fetch).
// ---------------------------------------------------------------------------
__global__ __launch_bounds__(512, 2)
void hsq_gemm_kernel(const unsigned short* __restrict__ Pb,
                     const unsigned short* __restrict__ W,
                     const float* __restrict__ l_coefs,
                     float2* __restrict__ part) {
    extern __shared__ unsigned short smem[];

    // bijective XCD swizzle (1024 % 8 == 0): consecutive wg on one XCD share k
    const int bid = blockIdx.x;
    const int wg  = (bid & 7) * 128 + (bid >> 3);
    const int k   = wg >> 4;              // 0..63
    const int rem = wg & 15;
    const int et  = rem >> 3;             // 0..1  (e-tile of 256)
    const int mt  = rem & 7;              // 0..7  (batch tile of 256)
    const int m0  = mt * 256;

    const int tid  = threadIdx.x;
    const int lane = tid & 63;
    const int w    = tid >> 6;            // 0..7
    const int wm   = w >> 2;              // 0..1
    const int wn   = w & 3;               // 0..3
    const int c    = lane & 15;
    const int quad = lane >> 4;

    const unsigned short* Wk = W + ((size_t)k * DIM + (size_t)et * 256) * DIM;

    // staging source (linear LDS dest; source carries the swizzle)
    const int scolb = ((tid & 7) * 16) ^ (((tid >> 3) & 7) << 4);   // bytes
    const unsigned short* pAs = Pb + (size_t)(m0 + (tid >> 3)) * DIM + (scolb >> 1);
    const unsigned short* pBs = Wk + (size_t)(tid >> 3) * DIM + (scolb >> 1);

    // frag read offsets (elements); row&7 == c&7 for every frag row
    const int xorv  = (c & 7) << 4;                              // bytes
    const int koff0 = ((0 * 64 + quad * 16) ^ xorv) >> 1;
    const int koff1 = ((1 * 64 + quad * 16) ^ xorv) >> 1;
    const int awoff = wm * 8192 + c * 64;
    const int bwoff = (wn >> 1) * 8192 + (wn & 1) * 4096 + c * 64;

#define STAGE_HALF(LDSELEM, GSRC) do {                                         \
    _Pragma("unroll")                                                          \
    for (int cc_ = 0; cc_ < 2; ++cc_) {                                        \
        __builtin_amdgcn_global_load_lds(                                      \
            (const __attribute__((address_space(1))) unsigned int*)            \
                ((GSRC) + (size_t)(cc_ * 64) * DIM),                           \
            (__attribute__((address_space(3))) unsigned int*)                  \
                (smem + (LDSELEM) + cc_ * 4096 + tid * 8),                     \
            16, 0, 0);                                                         \
    }                                                                          \
} while (0)

#define LOADB(BBASE) do {                                                      \
    _Pragma("unroll")                                                          \
    for (int ni_ = 0; ni_ < 4; ++ni_) {                                        \
        bfr[ni_][0] = *(const bf16x8*)(smem + (BBASE) + bwoff + ni_ * 1024 + koff0); \
        bfr[ni_][1] = *(const bf16x8*)(smem + (BBASE) + bwoff + ni_ * 1024 + koff1); \
    }                                                                          \
} while (0)

#define PHASE(ABASE, MI0, PRE_B, STAGE_AND_WAIT) do {                          \
    bf16x8 a00 = *(const bf16x8*)(smem + (ABASE) + awoff + (MI0) * 1024 + koff0);     \
    bf16x8 a01 = *(const bf16x8*)(smem + (ABASE) + awoff + (MI0) * 1024 + koff1);     \
    bf16x8 a10 = *(const bf16x8*)(smem + (ABASE) + awoff + ((MI0) + 1) * 1024 + koff0); \
    bf16x8 a11 = *(const bf16x8*)(smem + (ABASE) + awoff + ((MI0) + 1) * 1024 + koff1); \
    PRE_B;                                                                     \
    STAGE_AND_WAIT;                                                            \
    asm volatile("" ::: "memory");                                             \
    __builtin_amdgcn_s_barrier();                                              \
    asm volatile("" ::: "memory");                                             \
    __builtin_amdgcn_s_setprio(1);                                             \
    _Pragma("unroll")                                                          \
    for (int ni_ = 0; ni_ < 4; ++ni_) {                                        \
        acc[(MI0)][ni_]     = __builtin_amdgcn_mfma_f32_16x16x32_bf16(a00, bfr[ni_][0], acc[(MI0)][ni_], 0, 0, 0);     \
        acc[(MI0)][ni_]     = __builtin_amdgcn_mfma_f32_16x16x32_bf16(a01, bfr[ni_][1], acc[(MI0)][ni_], 0, 0, 0);     \
        acc[(MI0) + 1][ni_] = __builtin_amdgcn_mfma_f32_16x16x32_bf16(a10, bfr[ni_][0], acc[(MI0) + 1][ni_], 0, 0, 0); \
        acc[(MI0) + 1][ni_] = __builtin_amdgcn_mfma_f32_16x16x32_bf16(a11, bfr[ni_][1], acc[(MI0) + 1][ni_], 0, 0, 0); \
    }                                                                          \
    __builtin_amdgcn_s_setprio(0);                                             \
    asm volatile("" ::: "memory");                                             \
    __builtin_amdgcn_s_barrier();                                              \
    asm volatile("" ::: "memory");                                             \
} while (0)

    floatx4 acc[8][4];
#pragma unroll
    for (int mi = 0; mi < 8; ++mi)
#pragma unroll
        for (int ni = 0; ni < 4; ++ni)
            acc[mi][ni] = (floatx4){0.f, 0.f, 0.f, 0.f};

    bf16x8 bfr[4][2];

    // prologue: buf0 full (kt0) + buf1.B (kt1); wait buf0, leave buf1.B in flight
    STAGE_HALF(0,             pAs);
    STAGE_HALF(8192,          pAs + 128 * DIM);
    STAGE_HALF(16384,         pBs);
    STAGE_HALF(16384 + 8192,  pBs + 128 * DIM);
    STAGE_HALF(49152,         pBs + 64);
    STAGE_HALF(49152 + 8192,  pBs + 128 * DIM + 64);
    asm volatile("s_waitcnt vmcnt(4)" ::: "memory");
    __builtin_amdgcn_s_barrier();
    asm volatile("" ::: "memory");

    for (int it = 0; it < 4; ++it) {
        const unsigned short* pA1 = pAs + (size_t)(2 * it + 1) * 64;
        const unsigned short* pB2 = pBs + (size_t)(2 * it + 2) * 64;
        const unsigned short* pA2 = pAs + (size_t)(2 * it + 2) * 64;
        const unsigned short* pB3 = pBs + (size_t)(2 * it + 3) * 64;

        // ---- K-tile 2*it from buf0 ----
        PHASE(0, 0, LOADB(16384), { STAGE_HALF(32768, pA1); });
        PHASE(0, 2, ((void)0),    { STAGE_HALF(32768 + 8192, pA1 + 128 * DIM); });
        PHASE(0, 4, ((void)0),    { if (it < 3) STAGE_HALF(16384, pB2); });
        PHASE(0, 6, ((void)0), {
            if (it < 3) {
                STAGE_HALF(16384 + 8192, pB2 + 128 * DIM);
                asm volatile("s_waitcnt vmcnt(4)" ::: "memory");
            } else {
                asm volatile("s_waitcnt vmcnt(0)" ::: "memory");
            }
        });
        // ---- K-tile 2*it+1 from buf1 ----
        PHASE(32768, 0, LOADB(49152), { if (it < 3) STAGE_HALF(0, pA2); });
        PHASE(32768, 2, ((void)0),    { if (it < 3) STAGE_HALF(8192, pA2 + 128 * DIM); });
        PHASE(32768, 4, ((void)0),    { if (it < 3) STAGE_HALF(49152, pB3); });
        PHASE(32768, 6, ((void)0), {
            if (it < 3) {
                STAGE_HALF(49152 + 8192, pB3 + 128 * DIM);
                asm volatile("s_waitcnt vmcnt(4)" ::: "memory");
            }
        });
    }
#undef PHASE
#undef LOADB
#undef STAGE_HALF

    __syncthreads();

    // ---- Epilogue: pv = sum_e p*(0.5g+l), pg = sum_e (g+l)^2 over this et ----
    float lcv[4];
#pragma unroll
    for (int ni = 0; ni < 4; ++ni)
        lcv[ni] = l_coefs[(et * 256 + wn * 64 + ni * 16 + c) * NQ + k];

    const unsigned short* Pe = Pb + (size_t)(m0 + wm * 128) * DIM + et * 256 + wn * 64 + c;
    float* red = (float*)smem;   // reuse LDS: 8 waves x 128 rows x {pv,pg} = 8 KB

#pragma unroll
    for (int mi = 0; mi < 8; ++mi)
#pragma unroll
        for (int r = 0; r < 4; ++r) {
            const unsigned short* Prow = Pe + (size_t)(mi * 16 + quad * 4 + r) * DIM;
            float pv = 0.f, pg = 0.f;
#pragma unroll
            for (int ni = 0; ni < 4; ++ni) {
                const float g = acc[mi][ni][r];
                const float l = lcv[ni];
                pv += bf2f(Prow[ni * 16]) * (0.5f * g + l);
                const float gq = g + l;
                pg += gq * gq;
            }
#pragma unroll
            for (int off = 1; off < 16; off <<= 1) {
                pv += __shfl_xor(pv, off);
                pg += __shfl_xor(pg, off);
            }
            if (c == 0) {
                const int row16 = mi * 16 + quad * 4 + r;
                red[(w * 128 + row16) * 2 + 0] = pv;
                red[(w * 128 + row16) * 2 + 1] = pg;
            }
        }
    __syncthreads();

    if (tid < 256) {
        const int row16 = tid & 127;
        const int wmf   = tid >> 7;
        float pv = 0.f, pg = 0.f;
#pragma unroll
        for (int wnf = 0; wnf < 4; ++wnf) {
            const int wi = wmf * 4 + wnf;
            pv += red[(wi * 128 + row16) * 2 + 0];
            pg += red[(wi * 128 + row16) * 2 + 1];
        }
        part[((size_t)(et * NQ + k)) * BATCH + m0 + wmf * 128 + row16] =
            make_float2(pv, pg);
    }
}

// Final: block per k. Reduces npart[k][*] -> norm2 in-block, then combines the
// 2 e-range partials into scores (coalesced reads).
__global__ void hsq_final_kernel(const float2* __restrict__ part,
                                 const float* __restrict__ npart,
                                 const float* __restrict__ free_coefs,
                                 float* __restrict__ out) {
    const int k = blockIdx.x;
    const int t = threadIdx.x;
    __shared__ float ws[4];

    const float4* src = (const float4*)(npart + (size_t)k * 2048);
    const float4 a = src[t * 2], b = src[t * 2 + 1];
    float s = a.x + a.y + a.z + a.w + b.x + b.y + b.z + b.w;
#pragma unroll
    for (int off = 1; off < 64; off <<= 1) s += __shfl_xor(s, off);
    if ((t & 63) == 0) ws[t >> 6] = s;
    __syncthreads();
    const float nrm = sqrtf(ws[0] + ws[1] + ws[2] + ws[3]);
    const float fc  = free_coefs[k];

#pragma unroll
    for (int i = 0; i < 8; ++i) {
        const int bidx = i * 256 + t;
        float pv = 0.f, pg = 0.f;
#pragma unroll
        for (int eb = 0; eb < 2; ++eb) {
            const float2 p = part[((size_t)(eb * NQ + k)) * BATCH + bidx];
            pv += p.x; pg += p.y;
        }
        const float vals = fabsf(pv + fc);
        out[(size_t)bidx * NQ + k] = (sqrtf(0.25f * pg + vals * nrm) - 0.5f * sqrtf(pg)) / nrm;
    }
}

extern "C" void kernel_launch(void* const* d_in, const int* in_sizes, int n_in,
                              void* d_out, int out_size, void* d_ws, size_t ws_size,
                              hipStream_t stream) {
    const float* points     = (const float*)d_in[0];  // (2048, 512)
    const float* q_coefs    = (const float*)d_in[1];  // (131328, 64)
    const float* l_coefs    = (const float*)d_in[2];  // (512, 64)
    const float* free_coefs = (const float*)d_in[3];  // (1, 64)
    float* out = (float*)d_out;                       // (2048, 64)

    char* ws = (char*)d_ws;
    unsigned short* W  = (unsigned short*)ws;                              // 32 MiB
    unsigned short* Pb = (unsigned short*)(ws + 33554432);                 // 2 MiB
    float2*         part  = (float2*)(ws + 35651584);                      // 2 MiB
    float*          npart = (float*)(ws + 37748736);                       // 512 KiB

    // 128 KiB dynamic LDS needs the opt-in (one-time; not a stream op, safe
    // under graph capture).
    static bool attr_done = false;
    if (!attr_done) {
        (void)hipFuncSetAttribute((const void*)hsq_gemm_kernel,
                                  hipFuncAttributeMaxDynamicSharedMemorySize,
                                  131072);
        attr_done = true;
    }

    hsq_expand_kernel<<<dim3(512, 5), 512, 0, stream>>>(q_coefs, points, W, Pb, npart);
    hsq_gemm_kernel<<<dim3(1024), dim3(512), 131072, stream>>>(Pb, W, l_coefs, part);
    hsq_final_kernel<<<dim3(NQ), 256, 0, stream>>>(part, npart, free_coefs, out);
}